// Round 1
// baseline (530.779 us; speedup 1.0000x reference)
//
#include <hip/hip_runtime.h>
#include <math.h>

#define B 128
#define T 1024
#define H 256
#define L 16
#define INV_TEMP (1.0f/0.07f)
#define NEG_INF -1e30f

// Kernel 1: per-dialogue prototype sums + counts.
// One block per dialogue. Thread layout: wave g (of 4) handles token t0+j*4+g,
// lane handles channels [4*lane, 4*lane+4). float4 loads = 16B/lane coalesced.
// Accumulation into LDS via float atomics (ds_add_f32) since concurrent waves
// may share a label.
__global__ __launch_bounds__(256) void proto_kernel(
    const float* __restrict__ feat, const int* __restrict__ dlen,
    const int* __restrict__ labels, float* __restrict__ ws_proto,
    float* __restrict__ ws_cnt) {
  __shared__ float proto[L * H];   // 16 KB sums
  __shared__ int cnt[L];
  __shared__ int labs[T];          // 4 KB

  const int b = blockIdx.x;
  const int tid = threadIdx.x;

  for (int i = tid; i < L * H; i += 256) proto[i] = 0.f;
  if (tid < L) cnt[tid] = 0;
  const int* lb = labels + (size_t)b * T;
  for (int i = tid; i < T; i += 256) labs[i] = lb[i];
  __syncthreads();

  const int len = dlen[b];

  // counts
  for (int t = tid; t < len; t += 256) atomicAdd(&cnt[labs[t]], 1);

  const int g = tid >> 6;        // wave id 0..3
  const int lane = tid & 63;     // lane -> channel group
  const float4* f4 = (const float4*)(feat + (size_t)b * T * H);

  // 16 tokens per outer iter: 4 independent loads in flight per thread.
  for (int t0 = 0; t0 < len; t0 += 16) {
    float4 fr[4];
    int tv[4];
#pragma unroll
    for (int j = 0; j < 4; ++j) {
      int t = t0 + j * 4 + g;    // always < T (see loop-bound arithmetic)
      tv[j] = t;
      fr[j] = f4[(size_t)t * 64 + lane];
    }
#pragma unroll
    for (int j = 0; j < 4; ++j) {
      if (tv[j] < len) {
        const int lab = labs[tv[j]];
        float* p = &proto[lab * H + lane * 4];
        atomicAdd(p + 0, fr[j].x);
        atomicAdd(p + 1, fr[j].y);
        atomicAdd(p + 2, fr[j].z);
        atomicAdd(p + 3, fr[j].w);
      }
    }
  }
  __syncthreads();

  float* op = ws_proto + (size_t)b * L * H;
  for (int i = tid; i < L * H; i += 256) {
    const int l = i >> 8;
    const int c = cnt[l];
    op[i] = proto[i] * (c > 0 ? 1.f / (float)c : 0.f);
  }
  if (tid < L) ws_cnt[b * L + tid] = (float)cnt[tid];
}

// Kernel 2: per-token logits + log-softmax + loss.
// 4 blocks per dialogue, thread-per-token. Prototypes staged in LDS;
// proto reads are wave-uniform addresses -> LDS broadcast (conflict-free).
__global__ __launch_bounds__(256) void loss_kernel(
    const float* __restrict__ feat, const int* __restrict__ dlen,
    const int* __restrict__ labels, const float* __restrict__ ws_proto,
    const float* __restrict__ ws_cnt, float* __restrict__ out) {
  __shared__ float proto[L * H];
  __shared__ float present[L];
  __shared__ float red[256];

  const int bid = blockIdx.x;
  const int b = bid >> 2;
  const int seg = bid & 3;
  const int tid = threadIdx.x;

  const float* pp = ws_proto + (size_t)b * L * H;
  for (int i = tid; i < L * H; i += 256) proto[i] = pp[i];
  if (tid < L) present[tid] = ws_cnt[b * L + tid];
  __syncthreads();

  const int len = dlen[b];
  const int t = seg * 256 + tid;
  float tok = 0.f;

  if (t < len) {
    const float4* fv = (const float4*)(feat + ((size_t)b * T + t) * H);
    float dot[L];
#pragma unroll
    for (int l = 0; l < L; ++l) dot[l] = 0.f;

    for (int c = 0; c < H / 4; ++c) {
      const float4 f = fv[c];
#pragma unroll
      for (int l = 0; l < L; ++l) {
        const float4 p = *((const float4*)&proto[l * H + c * 4]);
        dot[l] += f.x * p.x + f.y * p.y + f.z * p.z + f.w * p.w;
      }
    }

    float lg[L];
#pragma unroll
    for (int l = 0; l < L; ++l)
      lg[l] = (present[l] > 0.f) ? dot[l] * INV_TEMP : NEG_INF;

    float m = lg[0];
#pragma unroll
    for (int l = 1; l < L; ++l) m = fmaxf(m, lg[l]);
    float se = 0.f;
#pragma unroll
    for (int l = 0; l < L; ++l) se += expf(lg[l] - m);
    const float lsp = m + logf(se);

    const int lab = labels[(size_t)b * T + t];
    float pos = 0.f;
#pragma unroll
    for (int l = 0; l < L; ++l) pos += (l == lab) ? lg[l] : 0.f;

    tok = lsp - pos;  // -(pos - lsp), TEMPERATURE/BASE_TEMPERATURE == 1
  }

  red[tid] = tok;
  __syncthreads();
#pragma unroll
  for (int s = 128; s > 0; s >>= 1) {
    if (tid < s) red[tid] += red[tid + s];
    __syncthreads();
  }
  if (tid == 0) {
    atomicAdd(out, red[0] / ((float)len * (float)B));
  }
}

extern "C" void kernel_launch(void* const* d_in, const int* in_sizes, int n_in,
                              void* d_out, int out_size, void* d_ws, size_t ws_size,
                              hipStream_t stream) {
  const float* feat = (const float*)d_in[0];
  const int* dlen = (const int*)d_in[1];
  const int* labels = (const int*)d_in[2];
  float* out = (float*)d_out;

  float* ws_proto = (float*)d_ws;                    // B*L*H floats = 2 MB
  float* ws_cnt = ws_proto + (size_t)B * L * H;      // B*L floats

  hipMemsetAsync(out, 0, sizeof(float), stream);
  proto_kernel<<<B, 256, 0, stream>>>(feat, dlen, labels, ws_proto, ws_cnt);
  loss_kernel<<<B * 4, 256, 0, stream>>>(feat, dlen, labels, ws_proto, ws_cnt, out);
}

// Round 2
// 252.090 us; speedup vs baseline: 2.1055x; 2.1055x over previous
//
#include <hip/hip_runtime.h>
#include <math.h>

#define B 128
#define T 1024
#define H 256
#define L 16
#define INV_TEMP (1.0f/0.07f)
#define NEG_INF -1e30f

// ws layout (floats/ints, contiguous):
//   ws_proto : float[B][L][H]      prototype SUMS (global-atomic accumulated)   2 MB
//   ws_cnt   : int[B][L]           label counts                                 8 KB
//   ws_dots  : float[2][B][T][L]   partial dots per H-half                      16 MB

// ---------------------------------------------------------------------------
// Kernel 1: prototype sums. grid = B * 2 chunks * 4 segs = 1024 blocks (4/CU).
// Block: 256 thr = 4 waves. Wave w owns 64 tokens of its segment; lane owns
// 2 channels of its 128-channel chunk (float2 = 8B/lane, 512B/wave coalesced).
// Wave-private LDS accumulator -> no atomics within wave (lanes hit distinct
// addresses; DS ops are in-order per wave so the per-token RMW chain is safe).
__global__ __launch_bounds__(256) void proto_kernel(
    const float* __restrict__ feat, const int* __restrict__ dlen,
    const int* __restrict__ labels, float* __restrict__ ws_proto,
    int* __restrict__ ws_cnt) {
  __shared__ float acc[4][L * 128];   // 32 KB, wave-private slabs
  __shared__ int labs[256];
  __shared__ int cnt[L];

  const int bx = blockIdx.x;
  const int b = bx >> 3;
  const int chunk = (bx >> 2) & 1;
  const int seg = bx & 3;
  const int tid = threadIdx.x;
  const int w = tid >> 6;
  const int lane = tid & 63;

  for (int i = tid; i < 4 * L * 128; i += 256) ((float*)acc)[i] = 0.f;
  labs[tid] = labels[(size_t)b * T + seg * 256 + tid];
  if (chunk == 0 && tid < L) cnt[tid] = 0;
  __syncthreads();

  const int len = dlen[b];

  if (chunk == 0 && (seg * 256 + tid) < len) atomicAdd(&cnt[labs[tid]], 1);

  int nt = len - seg * 256 - w * 64;   // tokens this wave must process
  if (nt > 64) nt = 64;
  const float2* fbase = (const float2*)(feat +
      ((size_t)b * T + seg * 256 + w * 64) * H + chunk * 128);
  float* a = acc[w];

  for (int j = 0; j < nt; ++j) {
    float2 f = fbase[(size_t)j * (H / 2) + lane];
    const int lab = labs[w * 64 + j];
    float2* p = (float2*)&a[lab * 128 + lane * 2];
    float2 v = *p;
    v.x += f.x; v.y += f.y;
    *p = v;
  }
  __syncthreads();

  // merge 4 wave slabs, global-atomic into ws_proto
  float* gp = ws_proto + (size_t)b * L * H + chunk * 128;
  for (int e = tid; e < L * 128; e += 256) {
    const float s = acc[0][e] + acc[1][e] + acc[2][e] + acc[3][e];
    const int l = e >> 7, c = e & 127;
    atomicAdd(&gp[l * H + c], s);
  }
  if (chunk == 0 && tid < L) atomicAdd(&ws_cnt[b * L + tid], cnt[tid]);
}

// ---------------------------------------------------------------------------
// Kernel 2: partial dots. grid = B * 2 token-halves * 2 H-halves = 512 blocks.
// Thread owns 2 tokens (tA, tA+256) x 16 labels over its 128-channel half.
// Proto half staged (divided) in LDS; uniform b128 reads amortized over 2
// tokens (8 fma per read). Token rows read as 8 back-to-back float4 per
// 128B-line so each L1 line is consumed while resident.
__global__ __launch_bounds__(256) void dots_kernel(
    const float* __restrict__ feat, const int* __restrict__ dlen,
    const float* __restrict__ ws_proto, const int* __restrict__ ws_cnt,
    float* __restrict__ ws_dots) {
  __shared__ float pr[L * 128];
  __shared__ int cnts[L];

  const int bx = blockIdx.x;
  const int b = bx >> 2;
  const int seg2 = (bx >> 1) & 1;
  const int half = bx & 1;
  const int tid = threadIdx.x;

  if (tid < L) cnts[tid] = ws_cnt[b * L + tid];
  __syncthreads();

  const float* gp = ws_proto + (size_t)b * L * H + half * 128;
  for (int i = tid; i < L * 128; i += 256) {
    const int l = i >> 7, c = i & 127;
    const int cn = cnts[l];
    pr[i] = gp[l * H + c] * (cn > 0 ? 1.f / (float)cn : 0.f);
  }
  __syncthreads();

  const int tA = seg2 * 512 + tid;      // second token = tA + 256
  const float4* fA = (const float4*)(feat + ((size_t)b * T + tA) * H + half * 128);
  const float4* fB = (const float4*)((const float*)fA + 256 * H);

  float dot[2][L];
#pragma unroll
  for (int l = 0; l < L; ++l) { dot[0][l] = 0.f; dot[1][l] = 0.f; }

  for (int c8 = 0; c8 < 4; ++c8) {
    float4 fa[8], fb[8];
#pragma unroll
    for (int j = 0; j < 8; ++j) {
      fa[j] = fA[c8 * 8 + j];
      fb[j] = fB[c8 * 8 + j];
    }
#pragma unroll
    for (int j = 0; j < 8; ++j) {
#pragma unroll
      for (int l = 0; l < L; ++l) {
        const float4 p = *(const float4*)&pr[l * 128 + c8 * 32 + j * 4];
        dot[0][l] += fa[j].x * p.x + fa[j].y * p.y + fa[j].z * p.z + fa[j].w * p.w;
        dot[1][l] += fb[j].x * p.x + fb[j].y * p.y + fb[j].z * p.z + fb[j].w * p.w;
      }
    }
  }

  float* dA = ws_dots + ((size_t)half * B * T + (size_t)b * T + tA) * L;
  float* dB = dA + 256 * L;
#pragma unroll
  for (int q = 0; q < 4; ++q) {
    ((float4*)dA)[q] = make_float4(dot[0][q*4], dot[0][q*4+1], dot[0][q*4+2], dot[0][q*4+3]);
    ((float4*)dB)[q] = make_float4(dot[1][q*4], dot[1][q*4+1], dot[1][q*4+2], dot[1][q*4+3]);
  }
}

// ---------------------------------------------------------------------------
// Kernel 3: combine halves, log-softmax, masked mean. grid = B*4 = 512 blocks.
__global__ __launch_bounds__(256) void loss_kernel(
    const int* __restrict__ dlen, const int* __restrict__ labels,
    const int* __restrict__ ws_cnt, const float* __restrict__ ws_dots,
    float* __restrict__ out) {
  __shared__ int cnts[L];
  __shared__ float red[256];

  const int b = blockIdx.x >> 2;
  const int seg = blockIdx.x & 3;
  const int tid = threadIdx.x;

  if (tid < L) cnts[tid] = ws_cnt[b * L + tid];
  __syncthreads();

  const int len = dlen[b];
  const int t = seg * 256 + tid;
  float tok = 0.f;

  if (t < len) {
    const float* d0 = ws_dots + ((size_t)b * T + t) * L;
    const float* d1 = d0 + (size_t)B * T * L;
    float lg[L];
#pragma unroll
    for (int l = 0; l < L; ++l) {
      const float d = d0[l] + d1[l];
      lg[l] = (cnts[l] > 0) ? d * INV_TEMP : NEG_INF;
    }
    float m = lg[0];
#pragma unroll
    for (int l = 1; l < L; ++l) m = fmaxf(m, lg[l]);
    float se = 0.f;
#pragma unroll
    for (int l = 0; l < L; ++l) se += expf(lg[l] - m);
    const float lsp = m + logf(se);

    const int lab = labels[(size_t)b * T + t];
    float pos = 0.f;
#pragma unroll
    for (int l = 0; l < L; ++l) pos += (l == lab) ? lg[l] : 0.f;

    tok = lsp - pos;
  }

  red[tid] = tok;
  __syncthreads();
#pragma unroll
  for (int s = 128; s > 0; s >>= 1) {
    if (tid < s) red[tid] += red[tid + s];
    __syncthreads();
  }
  if (tid == 0) atomicAdd(out, red[0] / ((float)len * (float)B));
}

extern "C" void kernel_launch(void* const* d_in, const int* in_sizes, int n_in,
                              void* d_out, int out_size, void* d_ws, size_t ws_size,
                              hipStream_t stream) {
  const float* feat = (const float*)d_in[0];
  const int* dlen = (const int*)d_in[1];
  const int* labels = (const int*)d_in[2];
  float* out = (float*)d_out;

  float* ws_proto = (float*)d_ws;                       // B*L*H floats
  int* ws_cnt = (int*)(ws_proto + (size_t)B * L * H);   // B*L ints
  float* ws_dots = (float*)(ws_cnt + (size_t)B * L);    // 2*B*T*L floats

  // zero proto sums + counts (poisoned to 0xAA before every replay)
  hipMemsetAsync(d_ws, 0, ((size_t)B * L * H + B * L) * sizeof(float), stream);
  hipMemsetAsync(out, 0, sizeof(float), stream);

  proto_kernel<<<B * 8, 256, 0, stream>>>(feat, dlen, labels, ws_proto, ws_cnt);
  dots_kernel<<<B * 4, 256, 0, stream>>>(feat, dlen, ws_proto, ws_cnt, ws_dots);
  loss_kernel<<<B * 4, 256, 0, stream>>>(dlen, labels, ws_cnt, ws_dots, out);
}

// Round 3
// 234.377 us; speedup vs baseline: 2.2646x; 1.0756x over previous
//
#include <hip/hip_runtime.h>
#include <math.h>

#define B 128
#define T 1024
#define H 256
#define L 16
#define INV_TEMP (1.0f/0.07f)
#define NEG_INF -1e30f

// ws layout (all disjoint, every read location written first -> no memset):
//   ws_pp   : float[B][4][L][H]   per-seg prototype partial sums   8 MB
//   ws_cntp : int[B][4][L]        per-seg label counts             32 KB
//   ws_dots : float[2][B][T][L]   partial dots per H-half          16 MB

// ---------------------------------------------------------------------------
// Kernel 1: prototype partial sums. grid = B * 2 chunks * 4 segs = 1024 blocks.
// Block owns a disjoint [b][seg][L][chunk*128..+128) slice -> plain stores, no
// atomics. Wave-private LDS accumulators (lanes hit distinct addresses; DS ops
// are in-order per wave so the per-token RMW chain is safe).
__global__ __launch_bounds__(256) void proto_kernel(
    const float* __restrict__ feat, const int* __restrict__ dlen,
    const int* __restrict__ labels, float* __restrict__ ws_pp,
    int* __restrict__ ws_cntp) {
  __shared__ float acc[4][L * 128];   // 32 KB
  __shared__ int labs[256];
  __shared__ int cnt[L];

  const int bx = blockIdx.x;
  const int b = bx >> 3;
  const int chunk = (bx >> 2) & 1;
  const int seg = bx & 3;
  const int tid = threadIdx.x;
  const int w = tid >> 6;
  const int lane = tid & 63;

  const int len = dlen[b];
  float* op = ws_pp + (((size_t)b * 4 + seg) * L) * H + chunk * 128;

  if (seg * 256 >= len) {
    // fully invalid segment: publish zeros, skip all loads
    for (int e = tid; e < L * 128; e += 256) op[(e >> 7) * H + (e & 127)] = 0.f;
    if (chunk == 0 && tid < L) ws_cntp[(b * 4 + seg) * L + tid] = 0;
    return;
  }

  for (int i = tid; i < 4 * L * 128; i += 256) ((float*)acc)[i] = 0.f;
  labs[tid] = labels[(size_t)b * T + seg * 256 + tid];
  if (tid < L) cnt[tid] = 0;
  __syncthreads();

  if (chunk == 0 && (seg * 256 + tid) < len) atomicAdd(&cnt[labs[tid]], 1);

  int nt = len - seg * 256 - w * 64;   // tokens this wave processes
  if (nt > 64) nt = 64;
  const float2* fbase = (const float2*)(feat +
      ((size_t)b * T + seg * 256 + w * 64) * H + chunk * 128);
  float* a = acc[w];

  int j = 0;
  for (; j + 4 <= nt; j += 4) {
    float2 f0 = fbase[(size_t)(j + 0) * (H / 2) + lane];
    float2 f1 = fbase[(size_t)(j + 1) * (H / 2) + lane];
    float2 f2 = fbase[(size_t)(j + 2) * (H / 2) + lane];
    float2 f3 = fbase[(size_t)(j + 3) * (H / 2) + lane];
    const int l0 = labs[w * 64 + j + 0];
    const int l1 = labs[w * 64 + j + 1];
    const int l2 = labs[w * 64 + j + 2];
    const int l3 = labs[w * 64 + j + 3];
    float2* p0 = (float2*)&a[l0 * 128 + lane * 2];
    { float2 v = *p0; v.x += f0.x; v.y += f0.y; *p0 = v; }
    float2* p1 = (float2*)&a[l1 * 128 + lane * 2];
    { float2 v = *p1; v.x += f1.x; v.y += f1.y; *p1 = v; }
    float2* p2 = (float2*)&a[l2 * 128 + lane * 2];
    { float2 v = *p2; v.x += f2.x; v.y += f2.y; *p2 = v; }
    float2* p3 = (float2*)&a[l3 * 128 + lane * 2];
    { float2 v = *p3; v.x += f3.x; v.y += f3.y; *p3 = v; }
  }
  for (; j < nt; ++j) {
    float2 f = fbase[(size_t)j * (H / 2) + lane];
    const int lab = labs[w * 64 + j];
    float2* p = (float2*)&a[lab * 128 + lane * 2];
    float2 v = *p; v.x += f.x; v.y += f.y; *p = v;
  }
  __syncthreads();

  for (int e = tid; e < L * 128; e += 256) {
    const float s = acc[0][e] + acc[1][e] + acc[2][e] + acc[3][e];
    op[(e >> 7) * H + (e & 127)] = s;
  }
  if (chunk == 0 && tid < L) ws_cntp[(b * 4 + seg) * L + tid] = cnt[tid];
}

// ---------------------------------------------------------------------------
// Kernel 2: partial dots. grid = B * 2 H-halves = 256 blocks, 256 thr,
// 4 tokens/thread -> 16 fma per uniform ds_read_b128 (LDS pipe halved).
// Staging sums the 4 seg partials and divides by counts (finalize fused).
__global__ __launch_bounds__(256) void dots_kernel(
    const float* __restrict__ feat, const float* __restrict__ ws_pp,
    const int* __restrict__ ws_cntp, float* __restrict__ ws_dots) {
  __shared__ float pr[L * 128];
  __shared__ int cnts[L];

  const int bx = blockIdx.x;
  const int b = bx >> 1;
  const int half = bx & 1;
  const int tid = threadIdx.x;

  if (tid < L) {
    const int* cp = ws_cntp + b * 4 * L + tid;
    cnts[tid] = cp[0] + cp[L] + cp[2 * L] + cp[3 * L];
  }
  __syncthreads();

  const float* gp = ws_pp + ((size_t)b * 4 * L) * H + half * 128;
  for (int i = tid; i < L * 128; i += 256) {
    const int l = i >> 7, c = i & 127;
    const float s = gp[l * H + c] + gp[(L + l) * H + c] +
                    gp[(2 * L + l) * H + c] + gp[(3 * L + l) * H + c];
    const int cn = cnts[l];
    pr[i] = s * (cn > 0 ? 1.f / (float)cn : 0.f);
  }
  __syncthreads();

  const float4* fv[4];
#pragma unroll
  for (int k = 0; k < 4; ++k) {
    const int t = k * 256 + tid;
    fv[k] = (const float4*)(feat + ((size_t)b * T + t) * H + half * 128);
  }

  float dot[4][L];
#pragma unroll
  for (int k = 0; k < 4; ++k)
#pragma unroll
    for (int l = 0; l < L; ++l) dot[k][l] = 0.f;

  for (int cb = 0; cb < 8; ++cb) {   // 4 quads (64B) per burst per token
    float4 f[4][4];
#pragma unroll
    for (int k = 0; k < 4; ++k)
#pragma unroll
      for (int q = 0; q < 4; ++q) f[k][q] = fv[k][cb * 4 + q];
#pragma unroll
    for (int q = 0; q < 4; ++q) {
#pragma unroll
      for (int l = 0; l < L; ++l) {
        const float4 p = *(const float4*)&pr[l * 128 + cb * 16 + q * 4];
#pragma unroll
        for (int k = 0; k < 4; ++k) {
          dot[k][l] += f[k][q].x * p.x + f[k][q].y * p.y +
                       f[k][q].z * p.z + f[k][q].w * p.w;
        }
      }
    }
  }

#pragma unroll
  for (int k = 0; k < 4; ++k) {
    const int t = k * 256 + tid;
    float4* d = (float4*)(ws_dots + (((size_t)half * B + b) * T + t) * L);
#pragma unroll
    for (int q = 0; q < 4; ++q)
      d[q] = make_float4(dot[k][q * 4], dot[k][q * 4 + 1],
                         dot[k][q * 4 + 2], dot[k][q * 4 + 3]);
  }
}

// ---------------------------------------------------------------------------
// Kernel 3: combine halves, log-softmax, masked mean. grid = B*4 = 512 blocks.
__global__ __launch_bounds__(256) void loss_kernel(
    const int* __restrict__ dlen, const int* __restrict__ labels,
    const int* __restrict__ ws_cntp, const float* __restrict__ ws_dots,
    float* __restrict__ out) {
  __shared__ int cnts[L];
  __shared__ float red[256];

  const int b = blockIdx.x >> 2;
  const int seg = blockIdx.x & 3;
  const int tid = threadIdx.x;

  if (tid < L) {
    const int* cp = ws_cntp + b * 4 * L + tid;
    cnts[tid] = cp[0] + cp[L] + cp[2 * L] + cp[3 * L];
  }
  __syncthreads();

  const int len = dlen[b];
  const int t = seg * 256 + tid;
  float tok = 0.f;

  if (t < len) {
    const float* d0 = ws_dots + ((size_t)b * T + t) * L;
    const float* d1 = d0 + (size_t)B * T * L;
    float lg[L];
#pragma unroll
    for (int l = 0; l < L; ++l) {
      const float d = d0[l] + d1[l];
      lg[l] = (cnts[l] > 0) ? d * INV_TEMP : NEG_INF;
    }
    float m = lg[0];
#pragma unroll
    for (int l = 1; l < L; ++l) m = fmaxf(m, lg[l]);
    float se = 0.f;
#pragma unroll
    for (int l = 0; l < L; ++l) se += expf(lg[l] - m);
    const float lsp = m + logf(se);

    const int lab = labels[(size_t)b * T + t];
    float pos = 0.f;
#pragma unroll
    for (int l = 0; l < L; ++l) pos += (l == lab) ? lg[l] : 0.f;

    tok = lsp - pos;
  }

  red[tid] = tok;
  __syncthreads();
#pragma unroll
  for (int s = 128; s > 0; s >>= 1) {
    if (tid < s) red[tid] += red[tid + s];
    __syncthreads();
  }
  if (tid == 0) atomicAdd(out, red[0] / ((float)len * (float)B));
}

extern "C" void kernel_launch(void* const* d_in, const int* in_sizes, int n_in,
                              void* d_out, int out_size, void* d_ws, size_t ws_size,
                              hipStream_t stream) {
  const float* feat = (const float*)d_in[0];
  const int* dlen = (const int*)d_in[1];
  const int* labels = (const int*)d_in[2];
  float* out = (float*)d_out;

  float* ws_pp = (float*)d_ws;                           // B*4*L*H floats
  int* ws_cntp = (int*)(ws_pp + (size_t)B * 4 * L * H);  // B*4*L ints
  float* ws_dots = (float*)(ws_cntp + (size_t)B * 4 * L);// 2*B*T*L floats

  hipMemsetAsync(out, 0, sizeof(float), stream);
  proto_kernel<<<B * 8, 256, 0, stream>>>(feat, dlen, labels, ws_pp, ws_cntp);
  dots_kernel<<<B * 2, 256, 0, stream>>>(feat, ws_pp, ws_cntp, ws_dots);
  loss_kernel<<<B * 4, 256, 0, stream>>>(dlen, labels, ws_cntp, ws_dots, out);
}

// Round 4
// 226.259 us; speedup vs baseline: 2.3459x; 1.0359x over previous
//
#include <hip/hip_runtime.h>
#include <math.h>

#define B 128
#define T 1024
#define H 256
#define L 16
#define INV_TEMP (1.0f/0.07f)
#define NEG_INF -1e30f

// ws layout (only seg<nseg regions are ever written/read -> no memset):
//   ws_pp   : float[B][4][L][H]   per-seg prototype partial sums   8 MB
//   ws_cntp : int[B][4][L]        per-seg label counts             32 KB
//   ws_dots : float[2][B][T][L]   partial dots per H-half          16 MB

// ---------------------------------------------------------------------------
// Kernel 1: prototype partial sums. grid = B * 2 chunks * 4 segs = 1024 blocks.
// Block owns a disjoint [b][seg][L][chunk*128..+128) slice -> plain stores, no
// atomics. Invalid segments exit immediately (consumers skip seg >= nseg).
__global__ __launch_bounds__(256) void proto_kernel(
    const float* __restrict__ feat, const int* __restrict__ dlen,
    const int* __restrict__ labels, float* __restrict__ ws_pp,
    int* __restrict__ ws_cntp) {
  __shared__ float acc[4][L * 128];   // 32 KB, wave-private slabs
  __shared__ int labs[256];
  __shared__ int cnt[L];

  const int bx = blockIdx.x;
  const int b = bx >> 3;
  const int chunk = (bx >> 2) & 1;
  const int seg = bx & 3;
  const int tid = threadIdx.x;
  const int w = tid >> 6;
  const int lane = tid & 63;

  const int len = dlen[b];
  if (seg * 256 >= len) return;   // fully invalid segment: nothing published

  for (int i = tid; i < 4 * L * 128; i += 256) ((float*)acc)[i] = 0.f;
  labs[tid] = labels[(size_t)b * T + seg * 256 + tid];
  if (tid < L) cnt[tid] = 0;
  __syncthreads();

  if (chunk == 0 && (seg * 256 + tid) < len) atomicAdd(&cnt[labs[tid]], 1);

  int nt = len - seg * 256 - w * 64;   // tokens this wave processes
  if (nt > 64) nt = 64;
  const float2* fbase = (const float2*)(feat +
      ((size_t)b * T + seg * 256 + w * 64) * H + chunk * 128);
  float* a = acc[w];

  int j = 0;
  for (; j + 4 <= nt; j += 4) {
    float2 f0 = fbase[(size_t)(j + 0) * (H / 2) + lane];
    float2 f1 = fbase[(size_t)(j + 1) * (H / 2) + lane];
    float2 f2 = fbase[(size_t)(j + 2) * (H / 2) + lane];
    float2 f3 = fbase[(size_t)(j + 3) * (H / 2) + lane];
    const int l0 = labs[w * 64 + j + 0];
    const int l1 = labs[w * 64 + j + 1];
    const int l2 = labs[w * 64 + j + 2];
    const int l3 = labs[w * 64 + j + 3];
    float2* p0 = (float2*)&a[l0 * 128 + lane * 2];
    { float2 v = *p0; v.x += f0.x; v.y += f0.y; *p0 = v; }
    float2* p1 = (float2*)&a[l1 * 128 + lane * 2];
    { float2 v = *p1; v.x += f1.x; v.y += f1.y; *p1 = v; }
    float2* p2 = (float2*)&a[l2 * 128 + lane * 2];
    { float2 v = *p2; v.x += f2.x; v.y += f2.y; *p2 = v; }
    float2* p3 = (float2*)&a[l3 * 128 + lane * 2];
    { float2 v = *p3; v.x += f3.x; v.y += f3.y; *p3 = v; }
  }
  for (; j < nt; ++j) {
    float2 f = fbase[(size_t)j * (H / 2) + lane];
    const int lab = labs[w * 64 + j];
    float2* p = (float2*)&a[lab * 128 + lane * 2];
    float2 v = *p; v.x += f.x; v.y += f.y; *p = v;
  }
  __syncthreads();

  float* op = ws_pp + (((size_t)b * 4 + seg) * L) * H + chunk * 128;
  for (int e = tid; e < L * 128; e += 256) {
    const float s = acc[0][e] + acc[1][e] + acc[2][e] + acc[3][e];
    op[(e >> 7) * H + (e & 127)] = s;
  }
  if (chunk == 0 && tid < L) ws_cntp[(b * 4 + seg) * L + tid] = cnt[tid];
}

// ---------------------------------------------------------------------------
// Kernel 2: partial dots. grid = B * 2 H-halves = 256 blocks, 256 thr,
// up to 4 tokens/thread; token-group k skipped by block-uniform k<nseg branch
// (unrolled, so dot[k][l] stays in registers). 16 fma per uniform ds_read_b128.
__global__ __launch_bounds__(256) void dots_kernel(
    const float* __restrict__ feat, const int* __restrict__ dlen,
    const float* __restrict__ ws_pp, const int* __restrict__ ws_cntp,
    float* __restrict__ ws_dots) {
  __shared__ float pr[L * 128];
  __shared__ int cnts[L];

  const int bx = blockIdx.x;
  const int b = bx >> 1;
  const int half = bx & 1;
  const int tid = threadIdx.x;

  const int len = dlen[b];
  const int nseg = (len + 255) >> 8;   // 1..4 valid segments

  if (tid < L) {
    const int* cp = ws_cntp + b * 4 * L + tid;
    int c = 0;
    for (int s = 0; s < nseg; ++s) c += cp[s * L];
    cnts[tid] = c;
  }
  __syncthreads();

  const float* gp = ws_pp + ((size_t)b * 4 * L) * H + half * 128;
  for (int i = tid; i < L * 128; i += 256) {
    const int l = i >> 7, c = i & 127;
    float s = 0.f;
    for (int sg = 0; sg < nseg; ++sg) s += gp[(sg * L + l) * H + c];
    const int cn = cnts[l];
    pr[i] = s * (cn > 0 ? 1.f / (float)cn : 0.f);
  }
  __syncthreads();

  const float4* fv[4];
#pragma unroll
  for (int k = 0; k < 4; ++k) {
    const int t = k * 256 + tid;
    fv[k] = (const float4*)(feat + ((size_t)b * T + t) * H + half * 128);
  }

  float dot[4][L];
#pragma unroll
  for (int k = 0; k < 4; ++k)
#pragma unroll
    for (int l = 0; l < L; ++l) dot[k][l] = 0.f;

  for (int cb = 0; cb < 8; ++cb) {   // 4 quads (64B) per burst per token
    float4 f[4][4];
#pragma unroll
    for (int k = 0; k < 4; ++k) {
      if (k < nseg) {                // block-uniform: skip dead token groups
#pragma unroll
        for (int q = 0; q < 4; ++q) f[k][q] = fv[k][cb * 4 + q];
      }
    }
#pragma unroll
    for (int q = 0; q < 4; ++q) {
#pragma unroll
      for (int l = 0; l < L; ++l) {
        const float4 p = *(const float4*)&pr[l * 128 + cb * 16 + q * 4];
#pragma unroll
        for (int k = 0; k < 4; ++k) {
          if (k < nseg) {
            dot[k][l] += f[k][q].x * p.x + f[k][q].y * p.y +
                         f[k][q].z * p.z + f[k][q].w * p.w;
          }
        }
      }
    }
  }

#pragma unroll
  for (int k = 0; k < 4; ++k) {
    const int t = k * 256 + tid;
    if (k < nseg && t < len) {
      float4* d = (float4*)(ws_dots + (((size_t)half * B + b) * T + t) * L);
#pragma unroll
      for (int q = 0; q < 4; ++q)
        d[q] = make_float4(dot[k][q * 4], dot[k][q * 4 + 1],
                           dot[k][q * 4 + 2], dot[k][q * 4 + 3]);
    }
  }
}

// ---------------------------------------------------------------------------
// Kernel 3: combine halves, log-softmax, masked mean. grid = B*4 = 512 blocks.
__global__ __launch_bounds__(256) void loss_kernel(
    const int* __restrict__ dlen, const int* __restrict__ labels,
    const int* __restrict__ ws_cntp, const float* __restrict__ ws_dots,
    float* __restrict__ out) {
  __shared__ int cnts[L];
  __shared__ float red[256];

  const int b = blockIdx.x >> 2;
  const int seg = blockIdx.x & 3;
  const int tid = threadIdx.x;

  const int len = dlen[b];
  if (seg * 256 >= len) return;        // contributes exactly 0
  const int nseg = (len + 255) >> 8;

  if (tid < L) {
    const int* cp = ws_cntp + b * 4 * L + tid;
    int c = 0;
    for (int s = 0; s < nseg; ++s) c += cp[s * L];
    cnts[tid] = c;
  }
  __syncthreads();

  const int t = seg * 256 + tid;
  float tok = 0.f;

  if (t < len) {
    const float* d0 = ws_dots + ((size_t)b * T + t) * L;
    const float* d1 = d0 + (size_t)B * T * L;
    float lg[L];
#pragma unroll
    for (int l = 0; l < L; ++l) {
      const float d = d0[l] + d1[l];
      lg[l] = (cnts[l] > 0) ? d * INV_TEMP : NEG_INF;
    }
    float m = lg[0];
#pragma unroll
    for (int l = 1; l < L; ++l) m = fmaxf(m, lg[l]);
    float se = 0.f;
#pragma unroll
    for (int l = 0; l < L; ++l) se += expf(lg[l] - m);
    const float lsp = m + logf(se);

    const int lab = labels[(size_t)b * T + t];
    float pos = 0.f;
#pragma unroll
    for (int l = 0; l < L; ++l) pos += (l == lab) ? lg[l] : 0.f;

    tok = lsp - pos;
  }

  red[tid] = tok;
  __syncthreads();
#pragma unroll
  for (int s = 128; s > 0; s >>= 1) {
    if (tid < s) red[tid] += red[tid + s];
    __syncthreads();
  }
  if (tid == 0) atomicAdd(out, red[0] / ((float)len * (float)B));
}

extern "C" void kernel_launch(void* const* d_in, const int* in_sizes, int n_in,
                              void* d_out, int out_size, void* d_ws, size_t ws_size,
                              hipStream_t stream) {
  const float* feat = (const float*)d_in[0];
  const int* dlen = (const int*)d_in[1];
  const int* labels = (const int*)d_in[2];
  float* out = (float*)d_out;

  float* ws_pp = (float*)d_ws;                           // B*4*L*H floats
  int* ws_cntp = (int*)(ws_pp + (size_t)B * 4 * L * H);  // B*4*L ints
  float* ws_dots = (float*)(ws_cntp + (size_t)B * 4 * L);// 2*B*T*L floats

  hipMemsetAsync(out, 0, sizeof(float), stream);
  proto_kernel<<<B * 8, 256, 0, stream>>>(feat, dlen, labels, ws_pp, ws_cntp);
  dots_kernel<<<B * 2, 256, 0, stream>>>(feat, dlen, ws_pp, ws_cntp, ws_dots);
  loss_kernel<<<B * 4, 256, 0, stream>>>(dlen, labels, ws_cntp, ws_dots, out);
}